// Round 1
// baseline (605.385 us; speedup 1.0000x reference)
//
#include <hip/hip_runtime.h>
#include <stdint.h>

typedef unsigned long long u64;

#define PTOT 1024
#define CF   512
#define NBOX 9216
#define NW   144
#define TOPK 300

__device__ __forceinline__ uint32_t score_key(float s) {
  uint32_t b = __float_as_uint(s);
  uint32_t o = (b & 0x80000000u) ? ~b : (b | 0x80000000u);
  return ~o;  // ascending in key == descending in score
}

#define FMA16() do { \
  acc[0][0] = fmaf(bv.x, av.x, acc[0][0]); \
  acc[0][1] = fmaf(bv.x, av.y, acc[0][1]); \
  acc[0][2] = fmaf(bv.x, av.z, acc[0][2]); \
  acc[0][3] = fmaf(bv.x, av.w, acc[0][3]); \
  acc[1][0] = fmaf(bv.y, av.x, acc[1][0]); \
  acc[1][1] = fmaf(bv.y, av.y, acc[1][1]); \
  acc[1][2] = fmaf(bv.y, av.z, acc[1][2]); \
  acc[1][3] = fmaf(bv.y, av.w, acc[1][3]); \
  acc[2][0] = fmaf(bv.z, av.x, acc[2][0]); \
  acc[2][1] = fmaf(bv.z, av.y, acc[2][1]); \
  acc[2][2] = fmaf(bv.z, av.z, acc[2][2]); \
  acc[2][3] = fmaf(bv.z, av.w, acc[2][3]); \
  acc[3][0] = fmaf(bv.w, av.x, acc[3][0]); \
  acc[3][1] = fmaf(bv.w, av.y, acc[3][1]); \
  acc[3][2] = fmaf(bv.w, av.z, acc[3][2]); \
  acc[3][3] = fmaf(bv.w, av.w, acc[3][3]); \
} while (0)

// ---------------- conv1: 16x16 stride16 VALID patchify + bias + relu ----------------
// feat[co][p], p = py*32+px.  Tile: 64 p x 64 co, 4x4 per thread. Grid (16,8).
__global__ __launch_bounds__(256) void k_conv1(const float* __restrict__ img,
                                               const float* __restrict__ w,
                                               const float* __restrict__ bias,
                                               float* __restrict__ feat) {
  __shared__ __align__(16) float As[32][72];
  __shared__ __align__(16) float Bs[32][72];
  const int t = threadIdx.x;
  const int pbase = blockIdx.x * 64;
  const int cobase = blockIdx.y * 64;
  const int pg = t & 15, cg = t >> 4;
  const int pp0 = pg * 4, cc0 = cg * 4;
  const int py0 = pbase >> 5;
  float acc[4][4] = {};
  for (int kb = 0; kb < 768; kb += 32) {           // k = c*256 + ky*16 + kx
    const int c = kb >> 8;
    const int ky0 = (kb >> 4) & 15;
#pragma unroll
    for (int l0 = 0; l0 < 2048; l0 += 256) {       // A: 32k x 64p
      int l = l0 + t;
      int seg = l >> 9, off = l & 511;             // 4 contiguous 512-float image rows
      int py_off = seg >> 1, ky_off = seg & 1;
      int row = (py0 + py_off) * 16 + ky0 + ky_off;
      float v = img[(c * 512 + row) * 512 + off];
      As[ky_off * 16 + (off & 15)][py_off * 32 + (off >> 4)] = v;
    }
#pragma unroll
    for (int l0 = 0; l0 < 2048; l0 += 256) {       // B: 32k x 64co
      int l = l0 + t;
      Bs[l & 31][l >> 5] = w[(cobase + (l >> 5)) * 768 + kb + (l & 31)];
    }
    __syncthreads();
#pragma unroll
    for (int kk = 0; kk < 32; ++kk) {
      float4 av = *(const float4*)&As[kk][pp0];
      float4 bv = *(const float4*)&Bs[kk][cc0];
      FMA16();
    }
    __syncthreads();
  }
#pragma unroll
  for (int i = 0; i < 4; ++i) {
    int co = cobase + cc0 + i;
    float bb = bias[co];
#pragma unroll
    for (int j = 0; j < 4; ++j)
      feat[co * PTOT + pbase + pp0 + j] = fmaxf(acc[i][j] + bb, 0.f);
  }
}

// ---------------- conv2: 3x3 SAME, split-K=2 partials (no bias/relu here) ----------------
// Grid (16,8,2). k-order: ci*9 + r, r = ky*3+kx.
__global__ __launch_bounds__(256) void k_conv2(const float* __restrict__ feat,
                                               const float* __restrict__ w,
                                               float* __restrict__ hidP) {
  __shared__ __align__(16) float As[36][72];
  __shared__ __align__(16) float Bs[36][72];
  const int t = threadIdx.x;
  const int pbase = blockIdx.x * 64;
  const int cobase = blockIdx.y * 64;
  const int z = blockIdx.z;
  const int cib = z * 256;
  const int pg = t & 15, cg = t >> 4;
  const int pp0 = pg * 4, cc0 = cg * 4;
  float acc[4][4] = {};
  for (int cb = 0; cb < 256; cb += 4) {            // K-chunk = 4 ci * 9 r = 36
#pragma unroll
    for (int l0 = 0; l0 < 2304; l0 += 256) {       // A: 36k x 64p with halo/zero-pad
      int l = l0 + t;
      int kk = l >> 6, pp = l & 63;
      int cii = kk / 9;
      int r = kk - cii * 9;
      int ry = r / 3;
      int dy = ry - 1, dx = (r - ry * 3) - 1;
      int p = pbase + pp;
      int py = (p >> 5) + dy, px = (p & 31) + dx;
      float v = 0.f;
      if ((unsigned)py < 32u && (unsigned)px < 32u)
        v = feat[(cib + cb + cii) * PTOT + py * 32 + px];
      As[kk][pp] = v;
    }
#pragma unroll
    for (int l0 = 0; l0 < 2304; l0 += 256) {       // B: contiguous in k
      int l = l0 + t;
      int cc = l / 36, kk = l - cc * 36;
      Bs[kk][cc] = w[(cobase + cc) * 4608 + (cib + cb) * 9 + kk];
    }
    __syncthreads();
#pragma unroll
    for (int kk = 0; kk < 36; ++kk) {
      float4 av = *(const float4*)&As[kk][pp0];
      float4 bv = *(const float4*)&Bs[kk][cc0];
      FMA16();
    }
    __syncthreads();
  }
#pragma unroll
  for (int i = 0; i < 4; ++i)
#pragma unroll
    for (int j = 0; j < 4; ++j)
      hidP[(z * CF + cobase + cc0 + i) * PTOT + pbase + pp0 + j] = acc[i][j];
}

// ---------------- reduce split-K + bias + relu ----------------
__global__ __launch_bounds__(256) void k_reduce(const float* __restrict__ hidP,
                                                const float* __restrict__ bias,
                                                float* __restrict__ hid) {
  int g = blockIdx.x * 256 + threadIdx.x;          // 524288 elems
  float v = hidP[g] + hidP[CF * PTOT + g] + bias[g >> 10];
  hid[g] = fmaxf(v, 0.f);
}

// ---------------- heads: fused 1x1 convs -> scores (cls ch 9..17) + deltas ----------------
// Grid 16 (64 p each). 48 virtual channels: 0..8 = cls[9..17], 9..44 = box, 45..47 dummy.
__global__ __launch_bounds__(256) void k_heads(const float* __restrict__ hid,
                                               const float* __restrict__ wcls,
                                               const float* __restrict__ bcls,
                                               const float* __restrict__ wbox,
                                               const float* __restrict__ bbox,
                                               float* __restrict__ scores,
                                               float* __restrict__ deltas) {
  __shared__ __align__(16) float As[32][68];
  __shared__ __align__(16) float Bs[32][48];
  const int t = threadIdx.x;
  const int pbase = blockIdx.x * 64;
  const int pg = t & 31, cg = t >> 5;              // 2 p x 6 ch per thread
  float acc[2][6] = {};
  for (int cb = 0; cb < 512; cb += 32) {
#pragma unroll
    for (int l0 = 0; l0 < 2048; l0 += 256) {
      int l = l0 + t;
      As[l >> 6][l & 63] = hid[(cb + (l >> 6)) * PTOT + pbase + (l & 63)];
    }
#pragma unroll
    for (int l0 = 0; l0 < 1536; l0 += 256) {
      int l = l0 + t;
      int ch = l >> 5, cil = l & 31;
      float v = 0.f;
      if (ch < 9) v = wcls[(9 + ch) * CF + cb + cil];
      else if (ch < 45) v = wbox[(ch - 9) * CF + cb + cil];
      Bs[cil][ch] = v;
    }
    __syncthreads();
#pragma unroll
    for (int kk = 0; kk < 32; ++kk) {
      float2 a2 = *(const float2*)&As[kk][pg * 2];
      const float* bp = &Bs[kk][cg * 6];
      float2 b0 = *(const float2*)&bp[0];
      float2 b1 = *(const float2*)&bp[2];
      float2 b2 = *(const float2*)&bp[4];
      acc[0][0] = fmaf(a2.x, b0.x, acc[0][0]);
      acc[0][1] = fmaf(a2.x, b0.y, acc[0][1]);
      acc[0][2] = fmaf(a2.x, b1.x, acc[0][2]);
      acc[0][3] = fmaf(a2.x, b1.y, acc[0][3]);
      acc[0][4] = fmaf(a2.x, b2.x, acc[0][4]);
      acc[0][5] = fmaf(a2.x, b2.y, acc[0][5]);
      acc[1][0] = fmaf(a2.y, b0.x, acc[1][0]);
      acc[1][1] = fmaf(a2.y, b0.y, acc[1][1]);
      acc[1][2] = fmaf(a2.y, b1.x, acc[1][2]);
      acc[1][3] = fmaf(a2.y, b1.y, acc[1][3]);
      acc[1][4] = fmaf(a2.y, b2.x, acc[1][4]);
      acc[1][5] = fmaf(a2.y, b2.y, acc[1][5]);
    }
    __syncthreads();
  }
#pragma unroll
  for (int pq = 0; pq < 2; ++pq) {
    int p = pbase + pg * 2 + pq;
#pragma unroll
    for (int m = 0; m < 6; ++m) {
      int ch = cg * 6 + m;
      float v = acc[pq][m];
      if (ch < 9) {
        scores[p * 9 + ch] = v + bcls[9 + ch];
      } else if (ch < 45) {
        int d = ch - 9;
        deltas[(p * 9 + (d >> 2)) * 4 + (d & 3)] = v + bbox[d];
      }
    }
  }
}

// ---------------- decode + clip ----------------
__global__ __launch_bounds__(256) void k_decode(const float* __restrict__ deltas,
                                                const float* __restrict__ anchors,
                                                float4* __restrict__ props) {
  int n = blockIdx.x * 256 + threadIdx.x;          // 9216 exact
  float4 a = ((const float4*)anchors)[n];
  float4 d = ((const float4*)deltas)[n];
  float wa = a.z - a.x, ha = a.w - a.y;
  float cxa = a.x + 0.5f * wa, cya = a.y + 0.5f * ha;
  float dw = fminf(fmaxf(d.z, -4.f), 4.f);
  float dh = fminf(fmaxf(d.w, -4.f), 4.f);
  float cx = cxa + d.x * wa, cy = cya + d.y * ha;
  float ww = wa * expf(dw), hh = ha * expf(dh);
  float x1 = fmaxf(cx - 0.5f * ww, 0.f);
  float y1 = fmaxf(cy - 0.5f * hh, 0.f);
  float x2 = fminf(cx + 0.5f * ww, 511.f);
  float y2 = fminf(cy + 0.5f * hh, 511.f);
  props[n] = make_float4(x1, y1, x2, y2);
}

// ---------------- bitonic sort, 3 stages ----------------
__global__ __launch_bounds__(1024) void k_sort1(const float* __restrict__ scores,
                                                u64* __restrict__ keys) {
  __shared__ u64 lds[8192];                        // exactly 64 KB
  const int t = threadIdx.x;
  const int base = blockIdx.x * 8192;
  const bool desc = (blockIdx.x == 1);
#pragma unroll
  for (int l0 = 0; l0 < 8192; l0 += 1024) {
    int l = l0 + t, g = base + l;
    u64 kv = ~0ull;
    if (g < NBOX) kv = ((u64)score_key(scores[g]) << 32) | (u64)g;
    lds[l] = kv;
  }
  for (int k = 2; k <= 8192; k <<= 1) {
    for (int j = k >> 1; j > 0; j >>= 1) {
      __syncthreads();
#pragma unroll
      for (int m = 0; m < 4; ++m) {
        int pr = m * 1024 + t;
        int i = ((pr & ~(j - 1)) << 1) | (pr & (j - 1));
        int l2 = i | j;
        bool ascBlk = ((i & k) == 0);
        bool dirAsc = desc ? !ascBlk : ascBlk;
        u64 x = lds[i], y = lds[l2];
        bool sw = dirAsc ? (x > y) : (x < y);
        if (sw) { lds[i] = y; lds[l2] = x; }
      }
    }
  }
  __syncthreads();
#pragma unroll
  for (int l0 = 0; l0 < 8192; l0 += 1024) {
    int l = l0 + t;
    keys[base + l] = lds[l];
  }
}

__global__ __launch_bounds__(256) void k_sort2(u64* __restrict__ keys) {
  int i = blockIdx.x * 256 + threadIdx.x;          // 8192 threads
  u64 x = keys[i], y = keys[i + 8192];
  if (x > y) { keys[i] = y; keys[i + 8192] = x; }
}

__global__ __launch_bounds__(1024) void k_sort3(const u64* __restrict__ keys,
                                                const float4* __restrict__ props,
                                                float4* __restrict__ boxesS) {
  __shared__ u64 lds[8192];
  const int t = threadIdx.x;
  const int base = blockIdx.x * 8192;
#pragma unroll
  for (int l0 = 0; l0 < 8192; l0 += 1024) {
    int l = l0 + t;
    lds[l] = keys[base + l];
  }
  for (int j = 4096; j > 0; j >>= 1) {
    __syncthreads();
#pragma unroll
    for (int m = 0; m < 4; ++m) {
      int pr = m * 1024 + t;
      int i = ((pr & ~(j - 1)) << 1) | (pr & (j - 1));
      int l2 = i | j;
      u64 x = lds[i], y = lds[l2];
      if (x > y) { lds[i] = y; lds[l2] = x; }
    }
  }
  __syncthreads();
#pragma unroll
  for (int l0 = 0; l0 < 8192; l0 += 1024) {
    int l = l0 + t, g = base + l;
    if (g < NBOX) {
      int idx = (int)(lds[l] & 0xffffffffull);
      boxesS[g] = props[idx];
    }
  }
}

// ---------------- IOU bitmask, word-major: mask[w*NBOX + i] ----------------
__global__ __launch_bounds__(64) void k_iou(const float4* __restrict__ boxesS,
                                            u64* __restrict__ mask) {
  int bi = blockIdx.x, bj = blockIdx.y;
  if (bj < bi) return;
  __shared__ float4 cb[64];
  int tid = threadIdx.x;
  cb[tid] = boxesS[bj * 64 + tid];
  __syncthreads();
  int i = bi * 64 + tid;
  float4 a = boxesS[i];
  float areaA = (a.z - a.x) * (a.w - a.y);
  u64 bits = 0;
#pragma unroll 4
  for (int jj = 0; jj < 64; ++jj) {
    int j = bj * 64 + jj;
    float4 c = cb[jj];
    float areaB = (c.z - c.x) * (c.w - c.y);
    float iw = fmaxf(fminf(a.z, c.z) - fmaxf(a.x, c.x), 0.f);
    float ih = fmaxf(fminf(a.w, c.w) - fmaxf(a.y, c.y), 0.f);
    float inter = iw * ih;
    float uni = areaA + areaB - inter + 1e-9f;
    float iou = inter / uni;                        // IEEE fp32 div (no fast-math)
    bits |= ((u64)((j > i) && (iou > 0.7f))) << jj;
  }
  mask[(size_t)bj * NBOX + i] = bits;
}

// ---------------- serial greedy NMS scan + output ----------------
__global__ __launch_bounds__(1024) void k_scan(const u64* __restrict__ mask,
                                               const float4* __restrict__ boxesS,
                                               float* __restrict__ out) {
  __shared__ u64 blk[32][145];                      // 32-row staging block (+pad)
  __shared__ u64 remvMir[NW];                       // mirror of suppression bitset
  __shared__ int keptList[TOPK];
  __shared__ int remList[TOPK];
  __shared__ int ctrl[4];                           // 0:stop 1:keptCount
  const int t = threadIdx.x;
  for (int wdx = t; wdx < NW; wdx += 1024) remvMir[wdx] = 0ull;
  if (t < 4) ctrl[t] = 0;
  __syncthreads();

  const int lane = t & 63;
  const int wave = t >> 6;
  u64 r0 = 0, r1 = 0, r2 = 0;                       // words lane, lane+64, lane+128
  u64 R = 0;                                        // broadcast of current word
  int keptCount = 0, remCount = 0;

  for (int b = 0; b < NBOX / 32; ++b) {
    const int rbase = b * 32;
    {                                               // load phase: all 16 waves
      int rloc = t & 31;
      int wbase = t >> 5;                           // 0..31
      int i = rbase + rloc;
      bool skip = ((remvMir[i >> 6] >> (i & 63)) & 1ull) != 0;
      if (!skip) {
#pragma unroll
        for (int q = 0; q < 5; ++q) {
          int w = wbase + q * 32;
          if (w < NW) blk[rloc][w] = mask[(size_t)w * NBOX + i];
        }
      }
    }
    __syncthreads();
    if (wave == 0) {                                // process phase: wave 0 only
      const int wcur = rbase >> 6;
      if ((rbase & 63) == 0) {                      // new 64-box word: refresh broadcast
        u64 v = (wcur < 64) ? r0 : ((wcur < 128) ? r1 : r2);
        R = __shfl(v, wcur & 63, 64);
      }
      for (int rl = 0; rl < 32; ++rl) {
        int i = rbase + rl;
        if (!((R >> (i & 63)) & 1ull)) {            // kept
          if (keptCount < TOPK && lane == 0) keptList[keptCount] = i;
          ++keptCount;
          u64 m0 = (lane >= wcur) ? blk[rl][lane] : 0ull;
          r0 |= m0;
          int w1 = lane + 64;
          r1 |= (w1 >= wcur) ? blk[rl][w1] : 0ull;
          int w2 = lane + 128;
          if (w2 < NW) r2 |= blk[rl][w2];           // w2 >= 128 > wcur always relevant
          R |= blk[rl][wcur];                       // uniform read
          if (keptCount >= TOPK) break;
        } else {                                    // removed
          if (remCount < TOPK && lane == 0) remList[remCount] = i;
          ++remCount;
        }
      }
      remvMir[lane] = r0;                           // publish mirror for loaders
      remvMir[lane + 64] = r1;
      if (lane < 16) remvMir[lane + 128] = r2;
      if (lane == 0) {
        if (keptCount >= TOPK) ctrl[0] = 1;
        ctrl[1] = keptCount;
      }
    }
    __syncthreads();
    if (ctrl[0]) break;
  }

  int kc = ctrl[1];
  if (kc > TOPK) kc = TOPK;
  for (int k = t; k < TOPK; k += 1024) {
    int src = (k < kc) ? keptList[k] : remList[k - kc];
    float4 bx = boxesS[src];
    out[k * 4 + 0] = bx.x;
    out[k * 4 + 1] = bx.y;
    out[k * 4 + 2] = bx.z;
    out[k * 4 + 3] = bx.w;
  }
}

extern "C" void kernel_launch(void* const* d_in, const int* in_sizes, int n_in,
                              void* d_out, int out_size, void* d_ws, size_t ws_size,
                              hipStream_t stream) {
  const float* img   = (const float*)d_in[0];
  const float* anch  = (const float*)d_in[1];
  const float* w_bb  = (const float*)d_in[2];
  const float* b_bb  = (const float*)d_in[3];
  const float* w_rpn = (const float*)d_in[4];
  const float* b_rpn = (const float*)d_in[5];
  const float* w_cls = (const float*)d_in[6];
  const float* b_cls = (const float*)d_in[7];
  const float* w_box = (const float*)d_in[8];
  const float* b_box = (const float*)d_in[9];

  char* ws = (char*)d_ws;
  // Phase-1 buffers (consumed before mask is written over the same region):
  float*  feat   = (float*)(ws);                                   // 2 MB
  float*  hidP   = (float*)(ws + ((size_t)2 << 20));               // 4 MB
  float*  hid    = (float*)(ws + ((size_t)6 << 20));               // 2 MB
  float*  scores = (float*)(ws + ((size_t)8 << 20));               // 36 KB
  float*  deltas = (float*)(ws + ((size_t)8 << 20) + (64u << 10)); // 144 KB
  float4* props  = (float4*)(ws + ((size_t)8 << 20) + (256u << 10));// 144 KB
  // Phase-2 buffers:
  u64*    mask   = (u64*)(ws);                                     // 10.62 MB (reuses phase-1)
  u64*    keys   = (u64*)(ws + ((size_t)11 << 20));                // 128 KB
  float4* boxesS = (float4*)(ws + ((size_t)11 << 20) + (256u << 10)); // 144 KB
  float*  out    = (float*)d_out;

  hipLaunchKernelGGL(k_conv1, dim3(16, 8), dim3(256), 0, stream, img, w_bb, b_bb, feat);
  hipLaunchKernelGGL(k_conv2, dim3(16, 8, 2), dim3(256), 0, stream, feat, w_rpn, hidP);
  hipLaunchKernelGGL(k_reduce, dim3(2048), dim3(256), 0, stream, hidP, b_rpn, hid);
  hipLaunchKernelGGL(k_heads, dim3(16), dim3(256), 0, stream, hid, w_cls, b_cls, w_box, b_box, scores, deltas);
  hipLaunchKernelGGL(k_decode, dim3(36), dim3(256), 0, stream, deltas, anch, props);
  hipLaunchKernelGGL(k_sort1, dim3(2), dim3(1024), 0, stream, scores, keys);
  hipLaunchKernelGGL(k_sort2, dim3(32), dim3(256), 0, stream, keys);
  hipLaunchKernelGGL(k_sort3, dim3(2), dim3(1024), 0, stream, keys, props, boxesS);
  hipLaunchKernelGGL(k_iou, dim3(144, 144), dim3(64), 0, stream, boxesS, mask);
  hipLaunchKernelGGL(k_scan, dim3(1), dim3(1024), 0, stream, mask, boxesS, out);
}

// Round 2
// 435.797 us; speedup vs baseline: 1.3891x; 1.3891x over previous
//
#include <hip/hip_runtime.h>
#include <stdint.h>

typedef unsigned long long u64;

#define PTOT 1024
#define CF   512
#define NBOX 9216
#define NW   144
#define TOPK 300

__device__ __forceinline__ uint32_t score_key(float s) {
  uint32_t b = __float_as_uint(s);
  uint32_t o = (b & 0x80000000u) ? ~b : (b | 0x80000000u);
  return ~o;  // ascending in key == descending in score
}

#define FMA16() do { \
  acc[0][0] = fmaf(bv.x, av.x, acc[0][0]); \
  acc[0][1] = fmaf(bv.x, av.y, acc[0][1]); \
  acc[0][2] = fmaf(bv.x, av.z, acc[0][2]); \
  acc[0][3] = fmaf(bv.x, av.w, acc[0][3]); \
  acc[1][0] = fmaf(bv.y, av.x, acc[1][0]); \
  acc[1][1] = fmaf(bv.y, av.y, acc[1][1]); \
  acc[1][2] = fmaf(bv.y, av.z, acc[1][2]); \
  acc[1][3] = fmaf(bv.y, av.w, acc[1][3]); \
  acc[2][0] = fmaf(bv.z, av.x, acc[2][0]); \
  acc[2][1] = fmaf(bv.z, av.y, acc[2][1]); \
  acc[2][2] = fmaf(bv.z, av.z, acc[2][2]); \
  acc[2][3] = fmaf(bv.z, av.w, acc[2][3]); \
  acc[3][0] = fmaf(bv.w, av.x, acc[3][0]); \
  acc[3][1] = fmaf(bv.w, av.y, acc[3][1]); \
  acc[3][2] = fmaf(bv.w, av.z, acc[3][2]); \
  acc[3][3] = fmaf(bv.w, av.w, acc[3][3]); \
} while (0)

// ---------------- weight transpose: wT[k][co] = w[co][k] ----------------
// Grid (168,16): bx<144 -> w_rpn (K=4608), else w_bb (K=768).
__global__ __launch_bounds__(256) void k_wt(const float* __restrict__ w_rpn,
                                            const float* __restrict__ w_bb,
                                            float* __restrict__ wT,
                                            float* __restrict__ wT1) {
  __shared__ float T[32][33];
  int bx = blockIdx.x;
  const float* src; float* dst; int K, kb;
  if (bx < 144) { src = w_rpn; dst = wT; K = 4608; kb = bx * 32; }
  else          { src = w_bb;  dst = wT1; K = 768; kb = (bx - 144) * 32; }
  const int cob = blockIdx.y * 32;
  const int tx = threadIdx.x & 31, ty = threadIdx.x >> 5;
#pragma unroll
  for (int r = 0; r < 32; r += 8)
    T[ty + r][tx] = src[(cob + ty + r) * K + kb + tx];
  __syncthreads();
#pragma unroll
  for (int r = 0; r < 32; r += 8)
    dst[(kb + ty + r) * 512 + cob + tx] = T[tx][ty + r];
}

// ---------------- conv1: 16x16 stride16 patchify, split-K over c (z=0..2) ----------------
// Tile 64p x 64co, 4x4/thread. Grid (16,8,3). Partials, bias/relu in reduce1.
__global__ __launch_bounds__(256) void k_conv1(const float* __restrict__ img,
                                               const float* __restrict__ wT1,
                                               float* __restrict__ featP) {
  __shared__ __align__(16) float As[32][72];
  __shared__ __align__(16) float Bs[32][64];
  const int t = threadIdx.x;
  const int pbase = blockIdx.x * 64;
  const int cobase = blockIdx.y * 64;
  const int z = blockIdx.z;                        // input channel c
  const int pg = t & 15, cg = t >> 4;
  const int pp0 = pg * 4, cc0 = cg * 4;
  const int py0 = pbase >> 5;
  float acc[4][4] = {};
  for (int kb = 0; kb < 256; kb += 32) {           // k-local = ky*16+kx
    const int ky0 = kb >> 4;
#pragma unroll
    for (int l0 = 0; l0 < 2048; l0 += 256) {       // A: 32k x 64p
      int l = l0 + t;
      int seg = l >> 9, off = l & 511;
      int py_off = seg >> 1, ky_off = seg & 1;
      int row = (py0 + py_off) * 16 + ky0 + ky_off;
      float v = img[(z * 512 + row) * 512 + off];
      As[ky_off * 16 + (off & 15)][py_off * 32 + (off >> 4)] = v;
    }
#pragma unroll
    for (int it = 0; it < 2; ++it) {               // B: 32k x 64co from wT1
      int idx4 = it * 256 + t;                     // 512 float4s
      int k = idx4 >> 4, co4 = (idx4 & 15) << 2;
      *(float4*)&Bs[k][co4] =
          *(const float4*)&wT1[(z * 256 + kb + k) * 512 + cobase + co4];
    }
    __syncthreads();
#pragma unroll
    for (int kk = 0; kk < 32; ++kk) {
      float4 av = *(const float4*)&As[kk][pp0];
      float4 bv = *(const float4*)&Bs[kk][cc0];
      FMA16();
    }
    __syncthreads();
  }
#pragma unroll
  for (int i = 0; i < 4; ++i) {
    float* o = &featP[((size_t)z * CF + cobase + cc0 + i) * PTOT + pbase + pp0];
    *(float4*)o = make_float4(acc[i][0], acc[i][1], acc[i][2], acc[i][3]);
  }
}

// ---------------- reduce1: feat = relu(sum_z featP + bias) ----------------
__global__ __launch_bounds__(256) void k_reduce1(const float* __restrict__ featP,
                                                 const float* __restrict__ bias,
                                                 float* __restrict__ feat) {
  int idx4 = blockIdx.x * 256 + threadIdx.x;       // 131072 float4s
  int co = idx4 >> 8;
  const float4* f = (const float4*)featP;
  float4 a = f[idx4];
  float4 b = f[idx4 + 131072];
  float4 c = f[idx4 + 262144];
  float bb = bias[co];
  float4 o;
  o.x = fmaxf(a.x + b.x + c.x + bb, 0.f);
  o.y = fmaxf(a.y + b.y + c.y + bb, 0.f);
  o.z = fmaxf(a.z + b.z + c.z + bb, 0.f);
  o.w = fmaxf(a.w + b.w + c.w + bb, 0.f);
  ((float4*)feat)[idx4] = o;
}

// ---------------- conv2: 3x3 SAME, halo-window A, 8x8 reg tile, split-K Z ----------------
// Tile 128p(4 rows) x 128co. Grid (8,4,Z). Thread: 8px x 8co.
__global__ __launch_bounds__(256) void k_conv2(const float* __restrict__ feat,
                                               const float* __restrict__ wT,
                                               float* __restrict__ hidP,
                                               int ciPerZ) {
  __shared__ __align__(16) float As[8][6][40];     // [ci][row(-1..4)][x+4: -4..35]
  __shared__ __align__(16) float Bs[72 * 128];     // [k=ci*9+r][co]
  const int t = threadIdx.x;
  const int pyb = blockIdx.x * 4;                  // output rows pyb..pyb+3
  const int cob = blockIdx.y * 128;
  const int z = blockIdx.z;
  const int cib = z * ciPerZ;
  const int pg = t & 15, cg = t >> 4;
  const int prow = pg >> 2, px0 = (pg & 3) * 8;
  const int co0 = cg * 8;
  float acc[8][8] = {};                            // [m=co][j=px]
  for (int cc = 0; cc < ciPerZ; cc += 8) {
    {                                              // stage A: 480 float4s
      int idx4 = t;
#pragma unroll
      for (int it = 0; it < 2; ++it, idx4 += 256) {
        if (idx4 < 480) {
          int ci = idx4 / 60;
          int rem = idx4 - ci * 60;
          int row = rem / 10;
          int col4 = (rem - row * 10) << 2;
          int x = col4 - 4;
          int gy = pyb + row - 1;
          float4 v = make_float4(0.f, 0.f, 0.f, 0.f);
          if (x >= 0 && x < 32 && gy >= 0 && gy < 32)
            v = *(const float4*)&feat[(cib + cc + ci) * PTOT + gy * 32 + x];
          *(float4*)&As[ci][row][col4] = v;
        }
      }
    }
    {                                              // stage B: 2304 float4s
      const int kg0 = (cib + cc) * 9;
      int idx4 = t;
#pragma unroll
      for (int it = 0; it < 9; ++it, idx4 += 256) {
        int k = idx4 >> 5;
        int co4 = (idx4 & 31) << 2;
        *(float4*)&Bs[k * 128 + co4] =
            *(const float4*)&wT[(kg0 + k) * 512 + cob + co4];
      }
    }
    __syncthreads();
#pragma unroll 1
    for (int ci = 0; ci < 8; ++ci) {
#pragma unroll
      for (int dy = 0; dy < 3; ++dy) {
        const float* Ar = &As[ci][prow + dy][px0];
        float rw[16];
        *(float4*)&rw[0]  = *(const float4*)&Ar[0];
        *(float4*)&rw[4]  = *(const float4*)&Ar[4];
        *(float4*)&rw[8]  = *(const float4*)&Ar[8];
        *(float4*)&rw[12] = *(const float4*)&Ar[12];
#pragma unroll
        for (int dx = 0; dx < 3; ++dx) {
          const float* Bp = &Bs[(ci * 9 + dy * 3 + dx) * 128 + co0];
          float4 b0 = *(const float4*)&Bp[0];
          float4 b1 = *(const float4*)&Bp[4];
          float bm[8] = {b0.x, b0.y, b0.z, b0.w, b1.x, b1.y, b1.z, b1.w};
#pragma unroll
          for (int m = 0; m < 8; ++m)
#pragma unroll
            for (int j = 0; j < 8; ++j)
              acc[m][j] = fmaf(rw[3 + dx + j], bm[m], acc[m][j]);
        }
      }
    }
    __syncthreads();
  }
  const int prowg = pyb + prow;
#pragma unroll
  for (int m = 0; m < 8; ++m) {
    int co = cob + co0 + m;
    float* o = &hidP[((size_t)z * CF + co) * PTOT + prowg * 32 + px0];
    *(float4*)&o[0] = make_float4(acc[m][0], acc[m][1], acc[m][2], acc[m][3]);
    *(float4*)&o[4] = make_float4(acc[m][4], acc[m][5], acc[m][6], acc[m][7]);
  }
}

// ---------------- reduce2: hid_t[p][co] = relu(sum_z hidP + bias), transposed ----------------
__global__ __launch_bounds__(256) void k_reduce2(const float* __restrict__ hidP,
                                                 const float* __restrict__ bias,
                                                 float* __restrict__ hid_t, int Z) {
  __shared__ float T[64][65];
  const int co0 = blockIdx.x * 64, p0 = blockIdx.y * 64;
  const int t = threadIdx.x;
#pragma unroll
  for (int it = 0; it < 4; ++it) {
    int idx4 = it * 256 + t;                       // 1024: 64co x 16 p-f4
    int co = idx4 >> 4, p4 = (idx4 & 15) << 2;
    float4 s = make_float4(0.f, 0.f, 0.f, 0.f);
    for (int zz = 0; zz < Z; ++zz) {
      float4 v = *(const float4*)&hidP[((size_t)zz * CF + co0 + co) * PTOT + p0 + p4];
      s.x += v.x; s.y += v.y; s.z += v.z; s.w += v.w;
    }
    float b = bias[co0 + co];
    T[co][p4 + 0] = fmaxf(s.x + b, 0.f);
    T[co][p4 + 1] = fmaxf(s.y + b, 0.f);
    T[co][p4 + 2] = fmaxf(s.z + b, 0.f);
    T[co][p4 + 3] = fmaxf(s.w + b, 0.f);
  }
  __syncthreads();
#pragma unroll
  for (int it = 0; it < 4; ++it) {
    int idx4 = it * 256 + t;                       // 64p x 16 co-f4
    int p = idx4 >> 4, co4 = (idx4 & 15) << 2;
    float4 o = make_float4(T[co4][p], T[co4 + 1][p], T[co4 + 2][p], T[co4 + 3][p]);
    *(float4*)&hid_t[(size_t)(p0 + p) * CF + co0 + co4] = o;
  }
}

// ---------------- heads: one wave per pixel, shuffle-reduced dots ----------------
__global__ __launch_bounds__(256) void k_heads(const float* __restrict__ hid_t,
                                               const float* __restrict__ wcls,
                                               const float* __restrict__ bcls,
                                               const float* __restrict__ wbox,
                                               const float* __restrict__ bbox,
                                               float* __restrict__ scores,
                                               float* __restrict__ deltas) {
  const int t = threadIdx.x;
  const int lane = t & 63, w = t >> 6;
  const int p = blockIdx.x * 4 + w;
  const float* hp = &hid_t[(size_t)p * CF + lane * 8];
  float4 h0 = *(const float4*)hp;
  float4 h1 = *(const float4*)(hp + 4);
#pragma unroll 1
  for (int ch = 0; ch < 45; ++ch) {
    const float* wp = (ch < 9) ? &wcls[(9 + ch) * CF] : &wbox[(ch - 9) * CF];
    float4 w0 = *(const float4*)(wp + lane * 8);
    float4 w1 = *(const float4*)(wp + lane * 8 + 4);
    float s = h0.x * w0.x + h0.y * w0.y + h0.z * w0.z + h0.w * w0.w +
              h1.x * w1.x + h1.y * w1.y + h1.z * w1.z + h1.w * w1.w;
#pragma unroll
    for (int off = 32; off >= 1; off >>= 1) s += __shfl_xor(s, off, 64);
    if (lane == 0) {
      if (ch < 9) scores[p * 9 + ch] = s + bcls[9 + ch];
      else        deltas[p * 36 + (ch - 9)] = s + bbox[ch - 9];
    }
  }
}

// ---------------- decode + clip ----------------
__global__ __launch_bounds__(256) void k_decode(const float* __restrict__ deltas,
                                                const float* __restrict__ anchors,
                                                float4* __restrict__ props) {
  int n = blockIdx.x * 256 + threadIdx.x;          // 9216 exact
  float4 a = ((const float4*)anchors)[n];
  float4 d = ((const float4*)deltas)[n];
  float wa = a.z - a.x, ha = a.w - a.y;
  float cxa = a.x + 0.5f * wa, cya = a.y + 0.5f * ha;
  float dw = fminf(fmaxf(d.z, -4.f), 4.f);
  float dh = fminf(fmaxf(d.w, -4.f), 4.f);
  float cx = cxa + d.x * wa, cy = cya + d.y * ha;
  float ww = wa * expf(dw), hh = ha * expf(dh);
  float x1 = fmaxf(cx - 0.5f * ww, 0.f);
  float y1 = fmaxf(cy - 0.5f * hh, 0.f);
  float x2 = fminf(cx + 0.5f * ww, 511.f);
  float y2 = fminf(cy + 0.5f * hh, 511.f);
  props[n] = make_float4(x1, y1, x2, y2);
}

// ---------------- bitonic sort, 3 stages ----------------
__global__ __launch_bounds__(1024) void k_sort1(const float* __restrict__ scores,
                                                u64* __restrict__ keys) {
  __shared__ u64 lds[8192];
  const int t = threadIdx.x;
  const int base = blockIdx.x * 8192;
  const bool desc = (blockIdx.x == 1);
#pragma unroll
  for (int l0 = 0; l0 < 8192; l0 += 1024) {
    int l = l0 + t, g = base + l;
    u64 kv = ~0ull;
    if (g < NBOX) kv = ((u64)score_key(scores[g]) << 32) | (u64)g;
    lds[l] = kv;
  }
  for (int k = 2; k <= 8192; k <<= 1) {
    for (int j = k >> 1; j > 0; j >>= 1) {
      __syncthreads();
#pragma unroll
      for (int m = 0; m < 4; ++m) {
        int pr = m * 1024 + t;
        int i = ((pr & ~(j - 1)) << 1) | (pr & (j - 1));
        int l2 = i | j;
        bool ascBlk = ((i & k) == 0);
        bool dirAsc = desc ? !ascBlk : ascBlk;
        u64 x = lds[i], y = lds[l2];
        bool sw = dirAsc ? (x > y) : (x < y);
        if (sw) { lds[i] = y; lds[l2] = x; }
      }
    }
  }
  __syncthreads();
#pragma unroll
  for (int l0 = 0; l0 < 8192; l0 += 1024) {
    int l = l0 + t;
    keys[base + l] = lds[l];
  }
}

__global__ __launch_bounds__(256) void k_sort2(u64* __restrict__ keys) {
  int i = blockIdx.x * 256 + threadIdx.x;          // 8192 threads
  u64 x = keys[i], y = keys[i + 8192];
  if (x > y) { keys[i] = y; keys[i + 8192] = x; }
}

__global__ __launch_bounds__(1024) void k_sort3(const u64* __restrict__ keys,
                                                const float4* __restrict__ props,
                                                float4* __restrict__ boxesS) {
  __shared__ u64 lds[8192];
  const int t = threadIdx.x;
  const int base = blockIdx.x * 8192;
#pragma unroll
  for (int l0 = 0; l0 < 8192; l0 += 1024) {
    int l = l0 + t;
    lds[l] = keys[base + l];
  }
  for (int j = 4096; j > 0; j >>= 1) {
    __syncthreads();
#pragma unroll
    for (int m = 0; m < 4; ++m) {
      int pr = m * 1024 + t;
      int i = ((pr & ~(j - 1)) << 1) | (pr & (j - 1));
      int l2 = i | j;
      u64 x = lds[i], y = lds[l2];
      if (x > y) { lds[i] = y; lds[l2] = x; }
    }
  }
  __syncthreads();
#pragma unroll
  for (int l0 = 0; l0 < 8192; l0 += 1024) {
    int l = l0 + t, g = base + l;
    if (g < NBOX) {
      int idx = (int)(lds[l] & 0xffffffffull);
      boxesS[g] = props[idx];
    }
  }
}

// ---------------- IOU bitmask, word-major: mask[w*NBOX + i] ----------------
__global__ __launch_bounds__(64) void k_iou(const float4* __restrict__ boxesS,
                                            u64* __restrict__ mask) {
  int bi = blockIdx.x, bj = blockIdx.y;
  if (bj < bi) return;
  __shared__ float4 cb[64];
  int tid = threadIdx.x;
  cb[tid] = boxesS[bj * 64 + tid];
  __syncthreads();
  int i = bi * 64 + tid;
  float4 a = boxesS[i];
  float areaA = (a.z - a.x) * (a.w - a.y);
  u64 bits = 0;
#pragma unroll 4
  for (int jj = 0; jj < 64; ++jj) {
    int j = bj * 64 + jj;
    float4 c = cb[jj];
    float areaB = (c.z - c.x) * (c.w - c.y);
    float iw = fmaxf(fminf(a.z, c.z) - fmaxf(a.x, c.x), 0.f);
    float ih = fmaxf(fminf(a.w, c.w) - fmaxf(a.y, c.y), 0.f);
    float inter = iw * ih;
    float uni = areaA + areaB - inter + 1e-9f;
    float iou = inter / uni;
    bits |= ((u64)((j > i) && (iou > 0.7f))) << jj;
  }
  mask[(size_t)bj * NBOX + i] = bits;
}

// ---------------- serial greedy NMS scan + output ----------------
__global__ __launch_bounds__(1024) void k_scan(const u64* __restrict__ mask,
                                               const float4* __restrict__ boxesS,
                                               float* __restrict__ out) {
  __shared__ u64 blk[32][145];
  __shared__ u64 remvMir[NW];
  __shared__ int keptList[TOPK];
  __shared__ int remList[TOPK];
  __shared__ int ctrl[4];
  const int t = threadIdx.x;
  for (int wdx = t; wdx < NW; wdx += 1024) remvMir[wdx] = 0ull;
  if (t < 4) ctrl[t] = 0;
  __syncthreads();

  const int lane = t & 63;
  const int wave = t >> 6;
  u64 r0 = 0, r1 = 0, r2 = 0;
  u64 R = 0;
  int keptCount = 0, remCount = 0;

  for (int b = 0; b < NBOX / 32; ++b) {
    const int rbase = b * 32;
    {
      int rloc = t & 31;
      int wbase = t >> 5;
      int i = rbase + rloc;
      bool skip = ((remvMir[i >> 6] >> (i & 63)) & 1ull) != 0;
      if (!skip) {
#pragma unroll
        for (int q = 0; q < 5; ++q) {
          int w = wbase + q * 32;
          if (w < NW) blk[rloc][w] = mask[(size_t)w * NBOX + i];
        }
      }
    }
    __syncthreads();
    if (wave == 0) {
      const int wcur = rbase >> 6;
      if ((rbase & 63) == 0) {
        u64 v = (wcur < 64) ? r0 : ((wcur < 128) ? r1 : r2);
        R = __shfl(v, wcur & 63, 64);
      }
      for (int rl = 0; rl < 32; ++rl) {
        int i = rbase + rl;
        if (!((R >> (i & 63)) & 1ull)) {
          if (keptCount < TOPK && lane == 0) keptList[keptCount] = i;
          ++keptCount;
          u64 m0 = (lane >= wcur) ? blk[rl][lane] : 0ull;
          r0 |= m0;
          int w1 = lane + 64;
          r1 |= (w1 >= wcur) ? blk[rl][w1] : 0ull;
          int w2 = lane + 128;
          if (w2 < NW) r2 |= blk[rl][w2];
          R |= blk[rl][wcur];
          if (keptCount >= TOPK) break;
        } else {
          if (remCount < TOPK && lane == 0) remList[remCount] = i;
          ++remCount;
        }
      }
      remvMir[lane] = r0;
      remvMir[lane + 64] = r1;
      if (lane < 16) remvMir[lane + 128] = r2;
      if (lane == 0) {
        if (keptCount >= TOPK) ctrl[0] = 1;
        ctrl[1] = keptCount;
      }
    }
    __syncthreads();
    if (ctrl[0]) break;
  }

  int kc = ctrl[1];
  if (kc > TOPK) kc = TOPK;
  for (int k = t; k < TOPK; k += 1024) {
    int src = (k < kc) ? keptList[k] : remList[k - kc];
    float4 bx = boxesS[src];
    out[k * 4 + 0] = bx.x;
    out[k * 4 + 1] = bx.y;
    out[k * 4 + 2] = bx.z;
    out[k * 4 + 3] = bx.w;
  }
}

extern "C" void kernel_launch(void* const* d_in, const int* in_sizes, int n_in,
                              void* d_out, int out_size, void* d_ws, size_t ws_size,
                              hipStream_t stream) {
  const float* img   = (const float*)d_in[0];
  const float* anch  = (const float*)d_in[1];
  const float* w_bb  = (const float*)d_in[2];
  const float* b_bb  = (const float*)d_in[3];
  const float* w_rpn = (const float*)d_in[4];
  const float* b_rpn = (const float*)d_in[5];
  const float* w_cls = (const float*)d_in[6];
  const float* b_cls = (const float*)d_in[7];
  const float* w_box = (const float*)d_in[8];
  const float* b_box = (const float*)d_in[9];

  char* ws = (char*)d_ws;
  // Pick split-K factor Z by available workspace (need = 22.8MB + Z*2MB).
  int Z = 16;
  if (ws_size < 22806528ull + 16ull * 2097152ull) Z = 8;
  if (ws_size < 22806528ull + 8ull * 2097152ull)  Z = 4;
  if (ws_size < 22806528ull + 4ull * 2097152ull)  Z = 2;
  if (ws_size < 22806528ull + 2ull * 2097152ull)  Z = 1;

  float* wT    = (float*)(ws);                      // [0, 9437184)
  float* wT1   = (float*)(ws + 9437184);            // 1.5 MB
  float* featP = (float*)(ws + 11010048);           // 6 MB
  float* feat  = (float*)(ws + 17301504);           // 2 MB
  float* hidP  = (float*)(ws + 19398656);           // Z * 2 MB
  char*  hte   = ws + 19398656 + (size_t)Z * 2097152;
  float* hid_t = (float*)hte;                       // 2 MB
  char*  tail  = hte + 2097152;
  float*  scores = (float*)(tail);
  float*  deltas = (float*)(tail + 0x40000);
  float4* props  = (float4*)(tail + 0x80000);
  u64*    keys   = (u64*)(tail + 0xC0000);
  float4* boxesS = (float4*)(tail + 0x100000);
  u64*    mask   = (u64*)(ws + 11010048);           // overlay featP/feat/hidP (dead by then)
  float*  out    = (float*)d_out;

  hipLaunchKernelGGL(k_wt, dim3(168, 16), dim3(256), 0, stream, w_rpn, w_bb, wT, wT1);
  hipLaunchKernelGGL(k_conv1, dim3(16, 8, 3), dim3(256), 0, stream, img, wT1, featP);
  hipLaunchKernelGGL(k_reduce1, dim3(512), dim3(256), 0, stream, featP, b_bb, feat);
  hipLaunchKernelGGL(k_conv2, dim3(8, 4, Z), dim3(256), 0, stream, feat, wT, hidP, 512 / Z);
  hipLaunchKernelGGL(k_reduce2, dim3(8, 16), dim3(256), 0, stream, hidP, b_rpn, hid_t, Z);
  hipLaunchKernelGGL(k_heads, dim3(256), dim3(256), 0, stream, hid_t, w_cls, b_cls, w_box, b_box, scores, deltas);
  hipLaunchKernelGGL(k_decode, dim3(36), dim3(256), 0, stream, deltas, anch, props);
  hipLaunchKernelGGL(k_sort1, dim3(2), dim3(1024), 0, stream, scores, keys);
  hipLaunchKernelGGL(k_sort2, dim3(32), dim3(256), 0, stream, keys);
  hipLaunchKernelGGL(k_sort3, dim3(2), dim3(1024), 0, stream, keys, props, boxesS);
  hipLaunchKernelGGL(k_iou, dim3(144, 144), dim3(64), 0, stream, boxesS, mask);
  hipLaunchKernelGGL(k_scan, dim3(1), dim3(1024), 0, stream, mask, boxesS, out);
}

// Round 3
// 399.098 us; speedup vs baseline: 1.5169x; 1.0920x over previous
//
#include <hip/hip_runtime.h>
#include <stdint.h>

typedef unsigned long long u64;

#define PTOT 1024
#define CF   512
#define NBOX 9216
#define NW   144
#define TOPK 300

__device__ __forceinline__ uint32_t score_key(float s) {
  uint32_t b = __float_as_uint(s);
  uint32_t o = (b & 0x80000000u) ? ~b : (b | 0x80000000u);
  return ~o;  // ascending in key == descending in score
}

#define FMA16() do { \
  acc[0][0] = fmaf(bv.x, av.x, acc[0][0]); \
  acc[0][1] = fmaf(bv.x, av.y, acc[0][1]); \
  acc[0][2] = fmaf(bv.x, av.z, acc[0][2]); \
  acc[0][3] = fmaf(bv.x, av.w, acc[0][3]); \
  acc[1][0] = fmaf(bv.y, av.x, acc[1][0]); \
  acc[1][1] = fmaf(bv.y, av.y, acc[1][1]); \
  acc[1][2] = fmaf(bv.y, av.z, acc[1][2]); \
  acc[1][3] = fmaf(bv.y, av.w, acc[1][3]); \
  acc[2][0] = fmaf(bv.z, av.x, acc[2][0]); \
  acc[2][1] = fmaf(bv.z, av.y, acc[2][1]); \
  acc[2][2] = fmaf(bv.z, av.z, acc[2][2]); \
  acc[2][3] = fmaf(bv.z, av.w, acc[2][3]); \
  acc[3][0] = fmaf(bv.w, av.x, acc[3][0]); \
  acc[3][1] = fmaf(bv.w, av.y, acc[3][1]); \
  acc[3][2] = fmaf(bv.w, av.z, acc[3][2]); \
  acc[3][3] = fmaf(bv.w, av.w, acc[3][3]); \
} while (0)

// ---------------- weight transpose: wT[k][co] = w[co][k] ----------------
__global__ __launch_bounds__(256) void k_wt(const float* __restrict__ w_rpn,
                                            const float* __restrict__ w_bb,
                                            float* __restrict__ wT,
                                            float* __restrict__ wT1) {
  __shared__ float T[32][33];
  int bx = blockIdx.x;
  const float* src; float* dst; int K, kb;
  if (bx < 144) { src = w_rpn; dst = wT; K = 4608; kb = bx * 32; }
  else          { src = w_bb;  dst = wT1; K = 768; kb = (bx - 144) * 32; }
  const int cob = blockIdx.y * 32;
  const int tx = threadIdx.x & 31, ty = threadIdx.x >> 5;
#pragma unroll
  for (int r = 0; r < 32; r += 8)
    T[ty + r][tx] = src[(cob + ty + r) * K + kb + tx];
  __syncthreads();
#pragma unroll
  for (int r = 0; r < 32; r += 8)
    dst[(kb + ty + r) * 512 + cob + tx] = T[tx][ty + r];
}

// ---------------- conv1: 16x16 stride16 patchify, split-K over c (z=0..2) ----------------
__global__ __launch_bounds__(256) void k_conv1(const float* __restrict__ img,
                                               const float* __restrict__ wT1,
                                               float* __restrict__ featP) {
  __shared__ __align__(16) float As[32][72];
  __shared__ __align__(16) float Bs[32][64];
  const int t = threadIdx.x;
  const int pbase = blockIdx.x * 64;
  const int cobase = blockIdx.y * 64;
  const int z = blockIdx.z;
  const int pg = t & 15, cg = t >> 4;
  const int pp0 = pg * 4, cc0 = cg * 4;
  const int py0 = pbase >> 5;
  float acc[4][4] = {};
  for (int kb = 0; kb < 256; kb += 32) {
    const int ky0 = kb >> 4;
#pragma unroll
    for (int l0 = 0; l0 < 2048; l0 += 256) {
      int l = l0 + t;
      int seg = l >> 9, off = l & 511;
      int py_off = seg >> 1, ky_off = seg & 1;
      int row = (py0 + py_off) * 16 + ky0 + ky_off;
      float v = img[(z * 512 + row) * 512 + off];
      As[ky_off * 16 + (off & 15)][py_off * 32 + (off >> 4)] = v;
    }
#pragma unroll
    for (int it = 0; it < 2; ++it) {
      int idx4 = it * 256 + t;
      int k = idx4 >> 4, co4 = (idx4 & 15) << 2;
      *(float4*)&Bs[k][co4] =
          *(const float4*)&wT1[(z * 256 + kb + k) * 512 + cobase + co4];
    }
    __syncthreads();
#pragma unroll
    for (int kk = 0; kk < 32; ++kk) {
      float4 av = *(const float4*)&As[kk][pp0];
      float4 bv = *(const float4*)&Bs[kk][cc0];
      FMA16();
    }
    __syncthreads();
  }
#pragma unroll
  for (int i = 0; i < 4; ++i) {
    float* o = &featP[((size_t)z * CF + cobase + cc0 + i) * PTOT + pbase + pp0];
    *(float4*)o = make_float4(acc[i][0], acc[i][1], acc[i][2], acc[i][3]);
  }
}

// ---------------- reduce1: feat = relu(sum_z featP + bias) ----------------
__global__ __launch_bounds__(256) void k_reduce1(const float* __restrict__ featP,
                                                 const float* __restrict__ bias,
                                                 float* __restrict__ feat) {
  int idx4 = blockIdx.x * 256 + threadIdx.x;
  int co = idx4 >> 8;
  const float4* f = (const float4*)featP;
  float4 a = f[idx4];
  float4 b = f[idx4 + 131072];
  float4 c = f[idx4 + 262144];
  float bb = bias[co];
  float4 o;
  o.x = fmaxf(a.x + b.x + c.x + bb, 0.f);
  o.y = fmaxf(a.y + b.y + c.y + bb, 0.f);
  o.z = fmaxf(a.z + b.z + c.z + bb, 0.f);
  o.w = fmaxf(a.w + b.w + c.w + bb, 0.f);
  ((float4*)feat)[idx4] = o;
}

// ---------------- conv2: 3x3 SAME, halo-window A, 8x8 reg tile, split-K Z ----------------
__global__ __launch_bounds__(256) void k_conv2(const float* __restrict__ feat,
                                               const float* __restrict__ wT,
                                               float* __restrict__ hidP,
                                               int ciPerZ) {
  __shared__ __align__(16) float As[8][6][40];
  __shared__ __align__(16) float Bs[72 * 128];
  const int t = threadIdx.x;
  const int pyb = blockIdx.x * 4;
  const int cob = blockIdx.y * 128;
  const int z = blockIdx.z;
  const int cib = z * ciPerZ;
  const int pg = t & 15, cg = t >> 4;
  const int prow = pg >> 2, px0 = (pg & 3) * 8;
  const int co0 = cg * 8;
  float acc[8][8] = {};
  for (int cc = 0; cc < ciPerZ; cc += 8) {
    {
      int idx4 = t;
#pragma unroll
      for (int it = 0; it < 2; ++it, idx4 += 256) {
        if (idx4 < 480) {
          int ci = idx4 / 60;
          int rem = idx4 - ci * 60;
          int row = rem / 10;
          int col4 = (rem - row * 10) << 2;
          int x = col4 - 4;
          int gy = pyb + row - 1;
          float4 v = make_float4(0.f, 0.f, 0.f, 0.f);
          if (x >= 0 && x < 32 && gy >= 0 && gy < 32)
            v = *(const float4*)&feat[(cib + cc + ci) * PTOT + gy * 32 + x];
          *(float4*)&As[ci][row][col4] = v;
        }
      }
    }
    {
      const int kg0 = (cib + cc) * 9;
      int idx4 = t;
#pragma unroll
      for (int it = 0; it < 9; ++it, idx4 += 256) {
        int k = idx4 >> 5;
        int co4 = (idx4 & 31) << 2;
        *(float4*)&Bs[k * 128 + co4] =
            *(const float4*)&wT[(kg0 + k) * 512 + cob + co4];
      }
    }
    __syncthreads();
#pragma unroll 1
    for (int ci = 0; ci < 8; ++ci) {
#pragma unroll
      for (int dy = 0; dy < 3; ++dy) {
        const float* Ar = &As[ci][prow + dy][px0];
        float rw[16];
        *(float4*)&rw[0]  = *(const float4*)&Ar[0];
        *(float4*)&rw[4]  = *(const float4*)&Ar[4];
        *(float4*)&rw[8]  = *(const float4*)&Ar[8];
        *(float4*)&rw[12] = *(const float4*)&Ar[12];
#pragma unroll
        for (int dx = 0; dx < 3; ++dx) {
          const float* Bp = &Bs[(ci * 9 + dy * 3 + dx) * 128 + co0];
          float4 b0 = *(const float4*)&Bp[0];
          float4 b1 = *(const float4*)&Bp[4];
          float bm[8] = {b0.x, b0.y, b0.z, b0.w, b1.x, b1.y, b1.z, b1.w};
#pragma unroll
          for (int m = 0; m < 8; ++m)
#pragma unroll
            for (int j = 0; j < 8; ++j)
              acc[m][j] = fmaf(rw[3 + dx + j], bm[m], acc[m][j]);
        }
      }
    }
    __syncthreads();
  }
  const int prowg = pyb + prow;
#pragma unroll
  for (int m = 0; m < 8; ++m) {
    int co = cob + co0 + m;
    float* o = &hidP[((size_t)z * CF + co) * PTOT + prowg * 32 + px0];
    *(float4*)&o[0] = make_float4(acc[m][0], acc[m][1], acc[m][2], acc[m][3]);
    *(float4*)&o[4] = make_float4(acc[m][4], acc[m][5], acc[m][6], acc[m][7]);
  }
}

// ---------------- reduce2: hid_t[p][co] = relu(sum_z hidP + bias), transposed ----------------
__global__ __launch_bounds__(256) void k_reduce2(const float* __restrict__ hidP,
                                                 const float* __restrict__ bias,
                                                 float* __restrict__ hid_t, int Z) {
  __shared__ float T[64][65];
  const int co0 = blockIdx.x * 64, p0 = blockIdx.y * 64;
  const int t = threadIdx.x;
#pragma unroll
  for (int it = 0; it < 4; ++it) {
    int idx4 = it * 256 + t;
    int co = idx4 >> 4, p4 = (idx4 & 15) << 2;
    float4 s = make_float4(0.f, 0.f, 0.f, 0.f);
    for (int zz = 0; zz < Z; ++zz) {
      float4 v = *(const float4*)&hidP[((size_t)zz * CF + co0 + co) * PTOT + p0 + p4];
      s.x += v.x; s.y += v.y; s.z += v.z; s.w += v.w;
    }
    float b = bias[co0 + co];
    T[co][p4 + 0] = fmaxf(s.x + b, 0.f);
    T[co][p4 + 1] = fmaxf(s.y + b, 0.f);
    T[co][p4 + 2] = fmaxf(s.z + b, 0.f);
    T[co][p4 + 3] = fmaxf(s.w + b, 0.f);
  }
  __syncthreads();
#pragma unroll
  for (int it = 0; it < 4; ++it) {
    int idx4 = it * 256 + t;
    int p = idx4 >> 4, co4 = (idx4 & 15) << 2;
    float4 o = make_float4(T[co4][p], T[co4 + 1][p], T[co4 + 2][p], T[co4 + 3][p]);
    *(float4*)&hid_t[(size_t)(p0 + p) * CF + co0 + co4] = o;
  }
}

// ---------------- heads: one wave per pixel, shuffle-reduced dots ----------------
__global__ __launch_bounds__(256) void k_heads(const float* __restrict__ hid_t,
                                               const float* __restrict__ wcls,
                                               const float* __restrict__ bcls,
                                               const float* __restrict__ wbox,
                                               const float* __restrict__ bbox,
                                               float* __restrict__ scores,
                                               float* __restrict__ deltas) {
  const int t = threadIdx.x;
  const int lane = t & 63, w = t >> 6;
  const int p = blockIdx.x * 4 + w;
  const float* hp = &hid_t[(size_t)p * CF + lane * 8];
  float4 h0 = *(const float4*)hp;
  float4 h1 = *(const float4*)(hp + 4);
#pragma unroll 1
  for (int ch = 0; ch < 45; ++ch) {
    const float* wp = (ch < 9) ? &wcls[(9 + ch) * CF] : &wbox[(ch - 9) * CF];
    float4 w0 = *(const float4*)(wp + lane * 8);
    float4 w1 = *(const float4*)(wp + lane * 8 + 4);
    float s = h0.x * w0.x + h0.y * w0.y + h0.z * w0.z + h0.w * w0.w +
              h1.x * w1.x + h1.y * w1.y + h1.z * w1.z + h1.w * w1.w;
#pragma unroll
    for (int off = 32; off >= 1; off >>= 1) s += __shfl_xor(s, off, 64);
    if (lane == 0) {
      if (ch < 9) scores[p * 9 + ch] = s + bcls[9 + ch];
      else        deltas[p * 36 + (ch - 9)] = s + bbox[ch - 9];
    }
  }
}

// ---------------- decode + clip ----------------
__global__ __launch_bounds__(256) void k_decode(const float* __restrict__ deltas,
                                                const float* __restrict__ anchors,
                                                float4* __restrict__ props) {
  int n = blockIdx.x * 256 + threadIdx.x;
  float4 a = ((const float4*)anchors)[n];
  float4 d = ((const float4*)deltas)[n];
  float wa = a.z - a.x, ha = a.w - a.y;
  float cxa = a.x + 0.5f * wa, cya = a.y + 0.5f * ha;
  float dw = fminf(fmaxf(d.z, -4.f), 4.f);
  float dh = fminf(fmaxf(d.w, -4.f), 4.f);
  float cx = cxa + d.x * wa, cy = cya + d.y * ha;
  float ww = wa * expf(dw), hh = ha * expf(dh);
  float x1 = fmaxf(cx - 0.5f * ww, 0.f);
  float y1 = fmaxf(cy - 0.5f * hh, 0.f);
  float x2 = fminf(cx + 0.5f * ww, 511.f);
  float y2 = fminf(cy + 0.5f * hh, 511.f);
  props[n] = make_float4(x1, y1, x2, y2);
}

// ---------------- bitonic sort, 3 stages ----------------
__global__ __launch_bounds__(1024) void k_sort1(const float* __restrict__ scores,
                                                u64* __restrict__ keys) {
  __shared__ u64 lds[8192];
  const int t = threadIdx.x;
  const int base = blockIdx.x * 8192;
  const bool desc = (blockIdx.x == 1);
#pragma unroll
  for (int l0 = 0; l0 < 8192; l0 += 1024) {
    int l = l0 + t, g = base + l;
    u64 kv = ~0ull;
    if (g < NBOX) kv = ((u64)score_key(scores[g]) << 32) | (u64)g;
    lds[l] = kv;
  }
  for (int k = 2; k <= 8192; k <<= 1) {
    for (int j = k >> 1; j > 0; j >>= 1) {
      __syncthreads();
#pragma unroll
      for (int m = 0; m < 4; ++m) {
        int pr = m * 1024 + t;
        int i = ((pr & ~(j - 1)) << 1) | (pr & (j - 1));
        int l2 = i | j;
        bool ascBlk = ((i & k) == 0);
        bool dirAsc = desc ? !ascBlk : ascBlk;
        u64 x = lds[i], y = lds[l2];
        bool sw = dirAsc ? (x > y) : (x < y);
        if (sw) { lds[i] = y; lds[l2] = x; }
      }
    }
  }
  __syncthreads();
#pragma unroll
  for (int l0 = 0; l0 < 8192; l0 += 1024) {
    int l = l0 + t;
    keys[base + l] = lds[l];
  }
}

__global__ __launch_bounds__(256) void k_sort2(u64* __restrict__ keys) {
  int i = blockIdx.x * 256 + threadIdx.x;
  u64 x = keys[i], y = keys[i + 8192];
  if (x > y) { keys[i] = y; keys[i + 8192] = x; }
}

__global__ __launch_bounds__(1024) void k_sort3(const u64* __restrict__ keys,
                                                const float4* __restrict__ props,
                                                float4* __restrict__ boxesS) {
  __shared__ u64 lds[8192];
  const int t = threadIdx.x;
  const int base = blockIdx.x * 8192;
#pragma unroll
  for (int l0 = 0; l0 < 8192; l0 += 1024) {
    int l = l0 + t;
    lds[l] = keys[base + l];
  }
  for (int j = 4096; j > 0; j >>= 1) {
    __syncthreads();
#pragma unroll
    for (int m = 0; m < 4; ++m) {
      int pr = m * 1024 + t;
      int i = ((pr & ~(j - 1)) << 1) | (pr & (j - 1));
      int l2 = i | j;
      u64 x = lds[i], y = lds[l2];
      if (x > y) { lds[i] = y; lds[l2] = x; }
    }
  }
  __syncthreads();
#pragma unroll
  for (int l0 = 0; l0 < 8192; l0 += 1024) {
    int l = l0 + t, g = base + l;
    if (g < NBOX) {
      int idx = (int)(lds[l] & 0xffffffffull);
      boxesS[g] = props[idx];
    }
  }
}

// ---------------- IOU bitmask, ROW-major: mask[i*NW + w] ----------------
__global__ __launch_bounds__(64) void k_iou(const float4* __restrict__ boxesS,
                                            u64* __restrict__ mask) {
  int bi = blockIdx.x, bj = blockIdx.y;
  if (bj < bi) return;
  __shared__ float4 cb[64];
  int tid = threadIdx.x;
  cb[tid] = boxesS[bj * 64 + tid];
  __syncthreads();
  int i = bi * 64 + tid;
  float4 a = boxesS[i];
  float areaA = (a.z - a.x) * (a.w - a.y);
  u64 bits = 0;
#pragma unroll 4
  for (int jj = 0; jj < 64; ++jj) {
    int j = bj * 64 + jj;
    float4 c = cb[jj];
    float areaB = (c.z - c.x) * (c.w - c.y);
    float iw = fmaxf(fminf(a.z, c.z) - fmaxf(a.x, c.x), 0.f);
    float ih = fmaxf(fminf(a.w, c.w) - fmaxf(a.y, c.y), 0.f);
    float inter = iw * ih;
    float uni = areaA + areaB - inter + 1e-9f;
    float iou = inter / uni;
    bits |= ((u64)((j > i) && (iou > 0.7f))) << jj;
  }
  mask[(size_t)i * NW + bj] = bits;
}

// ---------------- NMS scan v2: single wave, register-resident chain ----------------
// Bitset in registers: lane L holds words L (r0), L+64 (r1), L+128 (r2, L<16).
// Per 64-row span: coalesced diagonal-word load (prefetched), uniform-LDS chain,
// 4-way-pipelined coalesced row ORs. Output list derived from per-span keep masks.
__global__ __launch_bounds__(64) void k_scan(const u64* __restrict__ mask,
                                             const float4* __restrict__ boxesS,
                                             float* __restrict__ out) {
  __shared__ u64 Dbuf[64];
  __shared__ u64 keepArr[NW];
  __shared__ int pf[NW + 2];
  __shared__ int outIdx[TOPK];
  const int lane = threadIdx.x;

  u64 r0 = 0, r1 = 0, r2 = 0;
  int keptCount = 0;
  int stopSpan = NW - 1;

  // prefetch diagonal word for span 0: lane rl -> mask[rl][0]
  u64 dcur = mask[(size_t)lane * NW];

  for (int wb = 0; wb < NW; ++wb) {
    Dbuf[lane] = dcur;
    __syncthreads();

    // R = current suppression word wb (broadcast from owner lane)
    u64 v = (wb < 64) ? r0 : ((wb < 128) ? r1 : r2);
    u64 R = __shfl(v, wb & 63, 64);

    // prefetch next span's diagonal (overlaps with chain + OR below)
    u64 dnext = 0;
    if (wb + 1 < NW)
      dnext = mask[(size_t)((wb + 1) * 64 + lane) * NW + (wb + 1)];

    u64 keepmask = 0;
    if (R != ~0ull) {
      // serial keep-chain, 2 chunks of 32 uniform-preloaded diagonal words
#pragma unroll
      for (int c = 0; c < 2; ++c) {
        u64 d[32];
#pragma unroll
        for (int r = 0; r < 32; ++r) d[r] = Dbuf[c * 32 + r];
#pragma unroll
        for (int r = 0; r < 32; ++r) {
          int rl = c * 32 + r;
          u64 keep = ((R >> rl) & 1ull) ^ 1ull;
          keepmask |= keep << rl;
          R |= d[r] & (0ull - keep);
        }
      }
      // OR kept rows into the bitset, 4 rows in flight (coalesced 1152B rows)
      u64 km = keepmask;
      while (km) {
        int i0 = wb * 64 + __ffsll((long long)km) - 1; km &= km - 1;
        int i1 = i0, i2 = i0, i3 = i0;
        if (km) { i1 = wb * 64 + __ffsll((long long)km) - 1; km &= km - 1; }
        if (km) { i2 = wb * 64 + __ffsll((long long)km) - 1; km &= km - 1; }
        if (km) { i3 = wb * 64 + __ffsll((long long)km) - 1; km &= km - 1; }
        const u64* q0 = mask + (size_t)i0 * NW;
        const u64* q1 = mask + (size_t)i1 * NW;
        const u64* q2 = mask + (size_t)i2 * NW;
        const u64* q3 = mask + (size_t)i3 * NW;
        u64 a0 = q0[lane], a1 = q1[lane], a2 = q2[lane], a3 = q3[lane];
        u64 b0 = q0[lane + 64], b1 = q1[lane + 64], b2 = q2[lane + 64], b3 = q3[lane + 64];
        u64 c0 = 0, c1 = 0, c2 = 0, c3 = 0;
        if (lane < 16) {
          c0 = q0[lane + 128]; c1 = q1[lane + 128];
          c2 = q2[lane + 128]; c3 = q3[lane + 128];
        }
        r0 |= a0 | a1 | a2 | a3;
        r1 |= b0 | b1 | b2 | b3;
        r2 |= c0 | c1 | c2 | c3;
      }
      keptCount += __popcll(keepmask);
    }
    if (lane == 0) keepArr[wb] = keepmask;
    dcur = dnext;
    if (keptCount >= TOPK) { stopSpan = wb; break; }
  }

  __syncthreads();
  // prefix counts of kept per span (cheap serial on lane 0)
  if (lane == 0) {
    int acc = 0;
    for (int s = 0; s <= stopSpan; ++s) { pf[s] = acc; acc += __popcll(keepArr[s]); }
    pf[stopSpan + 1] = acc;
  }
  __syncthreads();
  const int keptTotal = pf[stopSpan + 1];

  // kept indices ascending -> slots [0, keptTotal)
  for (int s = lane; s <= stopSpan; s += 64) {
    u64 km = keepArr[s];
    int slot = pf[s];
    while (km && slot < TOPK) {
      int rl = __ffsll((long long)km) - 1; km &= km - 1;
      outIdx[slot++] = s * 64 + rl;
    }
  }
  // removed indices ascending -> slots [keptTotal, TOPK) (only if short of 300)
  if (keptTotal < TOPK) {
    for (int s = lane; s <= stopSpan; s += 64) {
      u64 rm = ~keepArr[s];
      int slot = keptTotal + s * 64 - pf[s];
      while (rm && slot < TOPK) {
        int rl = __ffsll((long long)rm) - 1; rm &= rm - 1;
        outIdx[slot++] = s * 64 + rl;
      }
    }
  }
  __syncthreads();
#pragma unroll
  for (int k0 = 0; k0 < TOPK + 63; k0 += 64) {
    int k = k0 + lane;
    if (k < TOPK) {
      float4 bx = boxesS[outIdx[k]];
      out[k * 4 + 0] = bx.x;
      out[k * 4 + 1] = bx.y;
      out[k * 4 + 2] = bx.z;
      out[k * 4 + 3] = bx.w;
    }
  }
}

extern "C" void kernel_launch(void* const* d_in, const int* in_sizes, int n_in,
                              void* d_out, int out_size, void* d_ws, size_t ws_size,
                              hipStream_t stream) {
  const float* img   = (const float*)d_in[0];
  const float* anch  = (const float*)d_in[1];
  const float* w_bb  = (const float*)d_in[2];
  const float* b_bb  = (const float*)d_in[3];
  const float* w_rpn = (const float*)d_in[4];
  const float* b_rpn = (const float*)d_in[5];
  const float* w_cls = (const float*)d_in[6];
  const float* b_cls = (const float*)d_in[7];
  const float* w_box = (const float*)d_in[8];
  const float* b_box = (const float*)d_in[9];

  char* ws = (char*)d_ws;
  int Z = 16;
  if (ws_size < 22806528ull + 16ull * 2097152ull) Z = 8;
  if (ws_size < 22806528ull + 8ull * 2097152ull)  Z = 4;
  if (ws_size < 22806528ull + 4ull * 2097152ull)  Z = 2;
  if (ws_size < 22806528ull + 2ull * 2097152ull)  Z = 1;

  float* wT    = (float*)(ws);                      // 9 MB
  float* wT1   = (float*)(ws + 9437184);            // 1.5 MB
  float* featP = (float*)(ws + 11010048);           // 6 MB
  float* feat  = (float*)(ws + 17301504);           // 2 MB
  float* hidP  = (float*)(ws + 19398656);           // Z * 2 MB
  char*  hte   = ws + 19398656 + (size_t)Z * 2097152;
  float* hid_t = (float*)hte;                       // 2 MB
  char*  tail  = hte + 2097152;
  float*  scores = (float*)(tail);
  float*  deltas = (float*)(tail + 0x40000);
  float4* props  = (float4*)(tail + 0x80000);
  u64*    keys   = (u64*)(tail + 0xC0000);
  float4* boxesS = (float4*)(tail + 0x100000);
  u64*    mask   = (u64*)(ws + 11010048);           // overlays featP/feat/hidP (dead)
  float*  out    = (float*)d_out;

  hipLaunchKernelGGL(k_wt, dim3(168, 16), dim3(256), 0, stream, w_rpn, w_bb, wT, wT1);
  hipLaunchKernelGGL(k_conv1, dim3(16, 8, 3), dim3(256), 0, stream, img, wT1, featP);
  hipLaunchKernelGGL(k_reduce1, dim3(512), dim3(256), 0, stream, featP, b_bb, feat);
  hipLaunchKernelGGL(k_conv2, dim3(8, 4, Z), dim3(256), 0, stream, feat, wT, hidP, 512 / Z);
  hipLaunchKernelGGL(k_reduce2, dim3(8, 16), dim3(256), 0, stream, hidP, b_rpn, hid_t, Z);
  hipLaunchKernelGGL(k_heads, dim3(256), dim3(256), 0, stream, hid_t, w_cls, b_cls, w_box, b_box, scores, deltas);
  hipLaunchKernelGGL(k_decode, dim3(36), dim3(256), 0, stream, deltas, anch, props);
  hipLaunchKernelGGL(k_sort1, dim3(2), dim3(1024), 0, stream, scores, keys);
  hipLaunchKernelGGL(k_sort2, dim3(32), dim3(256), 0, stream, keys);
  hipLaunchKernelGGL(k_sort3, dim3(2), dim3(1024), 0, stream, keys, props, boxesS);
  hipLaunchKernelGGL(k_iou, dim3(144, 144), dim3(64), 0, stream, boxesS, mask);
  hipLaunchKernelGGL(k_scan, dim3(1), dim3(64), 0, stream, mask, boxesS, out);
}